// Round 8
// baseline (266.741 us; speedup 1.0000x reference)
//
#include <hip/hip_runtime.h>
#include <hip/hip_bf16.h>

#define EMB 128

typedef __attribute__((ext_vector_type(8))) short short8;   // 8 bf16 (4 VGPRs)
typedef __attribute__((ext_vector_type(4))) float floatx4;  // MFMA C/D
typedef __attribute__((ext_vector_type(2))) float v2f;      // -> v_pk_fma_f32

// 26 valid (ok, di, ol) message combos: deltas = {1,2,-1,-2}, ol = ok+delta in [0,8)
static constexpr int OKv[26] = {0,0,1,1,1,2,2,2,2,3,3,3,3,4,4,4,4,5,5,5,5,6,6,6,7,7};
static constexpr int DIv[26] = {0,1,0,1,2,0,1,2,3,0,1,2,3,0,1,2,3,0,1,2,3,0,2,3,2,3};
static constexpr int OLv[26] = {1,2,2,3,0,3,4,1,0,4,5,2,1,5,6,3,2,6,7,4,3,7,5,4,6,5};

__device__ __forceinline__ v2f ldv2(const float* p) { return *(const v2f*)p; }

// round-to-nearest-even bf16 bits of x, kept in the TOP 16 bits (low 16 zero)
__device__ __forceinline__ unsigned bf16_rne_hi(float x) {
  unsigned u = __float_as_uint(x);
  return (u + 0x7FFFu + ((u >> 16) & 1u)) & 0xFFFF0000u;
}
// HW packed cvt: a -> low 16, b -> high 16 (v_cvt_pk_bf16_f32 on gfx950)
__device__ __forceinline__ unsigned cvt_pk_bf16(float a, float b) {
  __hip_bfloat162 h = __float22bfloat162_rn(make_float2(a, b));
  unsigned r; __builtin_memcpy(&r, &h, 4); return r;
}

union FragU { unsigned u[4]; uint4 q; short8 v; };

// LOGICAL CHANNEL PERMUTATION (R9-verified): MFMA C physical position
// (u, n=lane&15) carries logical channel L(u,n) = 2*((u>>1)*16 + n) + (u&1).
// Wave wv computes u in {2wv, 2wv+1} -> lane (wv, m16) holds the ADJACENT
// logical pair c0 = 2*(wv*16+m16), c0+1. Only wfrag bakes the permutation.
//
// SESSION NOTE (R22): latency-bound; per-wave wall ~53k cy vs ~8k issue.
// VALUBusy accounting shows ~3k VALU inst/wave — 2x hand count; surplus is
// the 26 emb_ea gathers RE-FOLDED into every layer (130 loads + addr calc):
// the allocator vetoed register residency twice (R15: stuck 104, R19:
// dropped to 80 — 80+52 crosses its 128-reg/4-wave heuristic). This round:
// opaque-asm pin (asm "+v") on each ea2[m] after load -> value becomes
// non-rematerializable, allocator MUST keep 52 VGPR live. VGPR ~130 caps
// 3 waves/SIMD = 12 waves/CU; measured residency 8.4 -> cap not binding.
// GATE: VGPR_Count >= 128, else pin failed (fallback: LDS-stage emb_ea).
// Falsified: occupancy-floor attrs (R1/R6), LDS size/barrier scope (R7/R11),
// epilogue (R8/R9), bank conflicts (R11), B-prefetch-in-phase (R12), VALU
// width (R13), wave-parallel widening (R14/R20), allocator-voluntary
// ea-hoist (R15/R19), asm-confounded sync (R18). Wins: bf16-A (R16, -17%),
// bf16-B (R17, -2%), (256,2) bounds floor (R19, -6.5%), clean 1-barrier
// dbuf + B-hoist (R21, -3%).

// Fused prep, grid 53 x 512:
//  b 0..31  : lin32 row b (4-way f-split + LDS reduce)
//  b 32..51 : w_conv -> B-fragment bf16 pre-pack with permuted N (160 frags)
//  b 52     : out[g] = b_pred[0]
__global__ __launch_bounds__(512) void prep_kernel(
    const float* __restrict__ emb_x,
    const float* __restrict__ w_ti,
    const float* __restrict__ b_ti,
    const float* __restrict__ w_conv,
    const float* __restrict__ b_pred,
    float* __restrict__ lin32,
    uint4* __restrict__ wfrag,
    float* __restrict__ out) {
  const int b = blockIdx.x, tid = threadIdx.x;
  if (b < 32) {
    __shared__ float red[4][EMB];
    const int e = tid & 127, fh = tid >> 7;      // fh in [0,4)
    const float* xr = emb_x + b * EMB;
    float s = 0.f;
    #pragma unroll 8
    for (int f = fh * 32; f < fh * 32 + 32; ++f)
      s = fmaf(xr[f], w_ti[f * EMB + e], s);
    red[fh][e] = s;
    __syncthreads();
    if (fh == 0)
      lin32[b * EMB + e] =
          b_ti[e] + ((red[0][e] + red[1][e]) + (red[2][e] + red[3][e]));
  } else if (b < 52) {
    const int id   = (b - 32) * 512 + tid;   // 160 frags * 64 lanes = 10240
    const int lane = id & 63;
    const int f    = id >> 6;         // frag index: [l][kt][u]
    const int u    = f & 7;           // N-tile (physical)
    const int t    = (f >> 3) & 3;    // K-tile
    const int l    = f >> 5;          // layer
    const int q    = lane >> 4, n = lane & 15;
    const int cN   = 2 * ((u >> 1) * 16 + n) + (u & 1);   // logical out channel
    unsigned w[4] = {0u, 0u, 0u, 0u};
    #pragma unroll
    for (int j = 0; j < 8; ++j) {
      const int kk = t * 32 + q * 8 + j;    // logical in channel (canonical)
      const float val = w_conv[l * (EMB * EMB) + kk * EMB + cN];
      const unsigned bb = bf16_rne_hi(val);
      w[j >> 1] |= (j & 1) ? bb : (bb >> 16);
    }
    wfrag[id] = make_uint4(w[0], w[1], w[2], w[3]);
  } else {
    if (tid < 64) out[tid] = b_pred[0];
  }
}

// R9 structure + packed fp32 (R13) + bf16 A/B (R16/R17) + bounds floor
// (R19) + 1-barrier dbuf/B-hoist (R21) + R22: asm-pinned ea2 registers.
__global__ __launch_bounds__(256, 2)
void i2gnn_mfma(
    const int* __restrict__ x,
    const int* __restrict__ edge_attr,
    const int* __restrict__ tuplefeat,
    const float* __restrict__ emb_x,
    const float* __restrict__ emb_tf,
    const float* __restrict__ emb_ea,
    const float* __restrict__ lin32,
    const float* __restrict__ b_conv,
    const float* __restrict__ w_pred,
    const uint4* __restrict__ wfrag,
    float* __restrict__ out)
{
  __shared__ __align__(16) unsigned fragA[2 * 64 * 68];   // 34816 B, dbuf

  const int tid = threadIdx.x;
  const int wv = tid >> 6, lane = tid & 63;
  const int m16 = lane & 15, q2 = lane >> 4;
  const int pc = wv * 16 + m16;        // logical pair-column this lane produces
  const int c0 = pc * 2;               // logical channels c0, c0+1

  const int i = blockIdx.x;
  const int ibase = i & ~63, io = i & 63;
  const int g = i >> 6;

  // 26 layer-invariant message coefficients, loaded once...
  v2f ea2[26];
  #pragma unroll
  for (int m = 0; m < 26; ++m) {
    const int kg = ibase + ((io + OKv[m]) & 63);
    const unsigned a = (unsigned)edge_attr[(kg << 2) + DIv[m]];
    ea2[m] = ldv2(emb_ea + a * EMB + c0);
  }
  // ...and PINNED (R22): opaque asm makes each value non-rematerializable,
  // so the allocator cannot re-fold the loads into the layer loop (it did
  // exactly that in R15/R19, burning 130 loads + addr calc per wave).
  #pragma unroll
  for (int m = 0; m < 26; ++m)
    asm volatile("" : "+v"(ea2[m]));

  // tupleinit in C-layout (packed): X2[mt][r] = v2f over channels (c0, c0+1);
  // pair ps = mt&1 (this lane: 2*q2+ps), k = (mt>>1)*4 + r.
  const int xi = x[i];
  const v2f xe = ldv2(emb_x + xi * EMB + c0);
  v2f lj[2];
  #pragma unroll
  for (int ps = 0; ps < 2; ++ps) {
    const int jn = ibase + ((io + 2 * q2 + ps) & 63);
    lj[ps] = ldv2(lin32 + x[jn] * EMB + c0);
  }
  v2f X2[4][4];   // [mt][r]
  #pragma unroll
  for (int mt = 0; mt < 4; ++mt) {
    const int ps = mt & 1, kb = (mt >> 1) * 4;
    const int t0 = (i * 8 + 2 * q2 + ps) << 3;
    const v2f xl = xe * lj[ps];
    #pragma unroll
    for (int r = 0; r < 4; ++r) {
      const int2 tf2 = *(const int2*)(tuplefeat + 2 * (t0 + kb + r));
      const int row = (c0 < 64) ? tf2.x : tf2.y;   // c0,c0+1 in same half
      const v2f tf = ldv2(emb_tf + row * 64 + (c0 & 63));
      X2[mt][r] = xl * tf;
    }
  }

  for (int l = 0; l < 5; ++l) {
    unsigned* fbuf = fragA + (l & 1) * 4352;   // this layer's A-frag buffer

    // ---- message pass, packed fp32 over (c0, c0+1), coefficients in regs ----
    v2f acc[2][8];   // [ps][k]
    #pragma unroll
    for (int ps = 0; ps < 2; ++ps)
      #pragma unroll
      for (int k = 0; k < 8; ++k) acc[ps][k] = (v2f){0.f, 0.f};
    #pragma unroll
    for (int m = 0; m < 26; ++m) {
      const v2f e = ea2[m];
      const int ok = OKv[m], ol = OLv[m];
      const int mtb = 2 * (ol >> 2), rl = ol & 3;   // compile-time consts
      acc[0][ok] += X2[mtb + 0][rl] * e;            // v_pk_fma_f32
      acc[1][ok] += X2[mtb + 1][rl] * e;
    }
    // ---- pack to bf16 (RNE), straight into A-frag LDS (dbuf side l&1) ----
    #pragma unroll
    for (int ps = 0; ps < 2; ++ps)
      #pragma unroll
      for (int k = 0; k < 8; ++k) {
        const v2f a = acc[ps][k];
        const int row = (ps + 2 * (k >> 2)) * 16 + q2 * 4 + (k & 3);
        fbuf[row * 68 + pc] = cvt_pk_bf16(a.x, a.y);
      }

    // ---- B(kt=0) hoisted ABOVE the barrier: its L2 latency hides under
    //      the barrier wait; dbuf gives the compiler a barrier-free span
    //      to float it even earlier (no dependence on fragA). ----
    FragU B0, B1;
    {
      const uint4* wp0 = wfrag + (((l * 4 + 0) * 8 + 2 * wv) << 6);
      B0.q = wp0[lane];  B1.q = wp0[64 + lane];
    }

    __syncthreads();   // the ONLY barrier this layer

    // ---- MFMA: wave computes u = {2wv, 2wv+1} for all 4 M-tiles ----
    floatx4 C[2][4];
    #pragma unroll
    for (int v = 0; v < 2; ++v)
      #pragma unroll
      for (int mt = 0; mt < 4; ++mt) C[v][mt] = (floatx4){0.f, 0.f, 0.f, 0.f};

    __builtin_amdgcn_s_setprio(1);
    #pragma unroll
    for (int kt = 0; kt < 4; ++kt) {
      FragU nB0, nB1;
      if (kt < 3) {   // rotate-prefetch next kt's B under this kt's MFMAs
        const uint4* wpn = wfrag + (((l * 4 + kt + 1) * 8 + 2 * wv) << 6);
        nB0.q = wpn[lane];  nB1.q = wpn[64 + lane];
      }
      #pragma unroll
      for (int mt = 0; mt < 4; ++mt) {
        const unsigned* fa = fbuf + (mt * 16 + m16) * 68 + kt * 16 + q2 * 4;
        FragU Ah;
        Ah.q = *(const uint4*)fa;
        C[0][mt] = __builtin_amdgcn_mfma_f32_16x16x32_bf16(Ah.v, B0.v, C[0][mt], 0, 0, 0);
        C[1][mt] = __builtin_amdgcn_mfma_f32_16x16x32_bf16(Ah.v, B1.v, C[1][mt], 0, 0, 0);
      }
      if (kt < 3) { B0 = nB0; B1 = nB1; }
    }
    __builtin_amdgcn_s_setprio(0);
    // NO second barrier (dbuf): next layer packs into the other buffer;
    // WAR on this buffer is ordered via barrier(l+1) — see R21 proof.

    // ---- residual + relu, packed: combine C[0]/C[1] into v2f lanes ----
    const v2f bc = ldv2(b_conv + l * EMB + c0);
    #pragma unroll
    for (int mt = 0; mt < 4; ++mt)
      #pragma unroll
      for (int r = 0; r < 4; ++r) {
        v2f o; o.x = C[0][mt][r]; o.y = C[1][mt][r];
        o += bc;                                     // v_pk_add_f32
        o.x = fmaxf(o.x, 0.f); o.y = fmaxf(o.y, 0.f);  // v_pk_max_f32
        X2[mt][r] += o;
      }
  }

  // ---- pooling: max over k per (v, pair), dot w_pred, xor-reduce, atomic ----
  const v2f wp = ldv2(w_pred + c0);
  v2f p0 = (v2f){-3.4e38f, -3.4e38f}, p1 = p0;
  #pragma unroll
  for (int r = 0; r < 4; ++r) {
    p0.x = fmaxf(p0.x, fmaxf(X2[0][r].x, X2[2][r].x));
    p0.y = fmaxf(p0.y, fmaxf(X2[0][r].y, X2[2][r].y));
    p1.x = fmaxf(p1.x, fmaxf(X2[1][r].x, X2[3][r].x));
    p1.y = fmaxf(p1.y, fmaxf(X2[1][r].y, X2[3][r].y));
  }
  const v2f ps = (p0 + p1) * wp;
  float s = ps.x + ps.y;
  #pragma unroll
  for (int off = 32; off; off >>= 1) s += __shfl_xor(s, off, 64);
  if (lane == 0) atomicAdd(out + g, s);
}

extern "C" void kernel_launch(void* const* d_in, const int* in_sizes, int n_in,
                              void* d_out, int out_size, void* d_ws, size_t ws_size,
                              hipStream_t stream) {
  const int*   x         = (const int*)d_in[0];
  const int*   edge_attr = (const int*)d_in[1];
  const int*   tuplefeat = (const int*)d_in[2];
  const float* emb_x     = (const float*)d_in[12];
  const float* emb_ea    = (const float*)d_in[13];
  const float* emb_tf    = (const float*)d_in[14];
  const float* w_ti      = (const float*)d_in[15];
  const float* b_ti      = (const float*)d_in[16];
  const float* w_conv    = (const float*)d_in[17];
  const float* b_conv    = (const float*)d_in[18];
  const float* w_pred    = (const float*)d_in[19];
  const float* b_pred    = (const float*)d_in[20];
  float* out = (float*)d_out;
  float* lin32 = (float*)d_ws;                               // 32*128 fp32 = 16 KB
  uint4* wfrag = (uint4*)((char*)d_ws + 32 * EMB * 4);       // 160 KB B-fragments

  hipLaunchKernelGGL(prep_kernel, dim3(53), dim3(512), 0, stream,
                     emb_x, w_ti, b_ti, w_conv, b_pred, lin32, wfrag, out);
  hipLaunchKernelGGL(i2gnn_mfma, dim3(4096), dim3(256), 0, stream,
                     x, edge_attr, tuplefeat, emb_x, emb_tf, emb_ea, lin32,
                     b_conv, w_pred, wfrag, out);
}

// Round 9
// 258.510 us; speedup vs baseline: 1.0318x; 1.0318x over previous
//
#include <hip/hip_runtime.h>
#include <hip/hip_bf16.h>

#define EMB 128

typedef __attribute__((ext_vector_type(8))) short short8;   // 8 bf16 (4 VGPRs)
typedef __attribute__((ext_vector_type(4))) float floatx4;  // MFMA C/D
typedef __attribute__((ext_vector_type(2))) float v2f;      // -> v_pk_fma_f32

// 26 valid (ok, di, ol) message combos: deltas = {1,2,-1,-2}, ol = ok+delta in [0,8)
static constexpr int OKv[26] = {0,0,1,1,1,2,2,2,2,3,3,3,3,4,4,4,4,5,5,5,5,6,6,6,7,7};
static constexpr int DIv[26] = {0,1,0,1,2,0,1,2,3,0,1,2,3,0,1,2,3,0,1,2,3,0,2,3,2,3};
static constexpr int OLv[26] = {1,2,2,3,0,3,4,1,0,4,5,2,1,5,6,3,2,6,7,4,3,7,5,4,6,5};

__device__ __forceinline__ v2f ldv2(const float* p) { return *(const v2f*)p; }

// round-to-nearest-even bf16 bits of x, kept in the TOP 16 bits (low 16 zero)
__device__ __forceinline__ unsigned bf16_rne_hi(float x) {
  unsigned u = __float_as_uint(x);
  return (u + 0x7FFFu + ((u >> 16) & 1u)) & 0xFFFF0000u;
}
// HW packed cvt: a -> low 16, b -> high 16 (v_cvt_pk_bf16_f32 on gfx950)
__device__ __forceinline__ unsigned cvt_pk_bf16(float a, float b) {
  __hip_bfloat162 h = __float22bfloat162_rn(make_float2(a, b));
  unsigned r; __builtin_memcpy(&r, &h, 4); return r;
}

union FragU { unsigned u[4]; uint4 q; short8 v; };

// LOGICAL CHANNEL PERMUTATION (R9-verified): MFMA C physical position
// (u, n=lane&15) carries logical channel L(u,n) = 2*((u>>1)*16 + n) + (u&1).
// Wave wv computes u in {2wv, 2wv+1} -> lane (wv, m16) holds the ADJACENT
// logical pair c0 = 2*(wv*16+m16), c0+1. Only wfrag bakes the permutation.
//
// SESSION NOTE (R23): latency-bound; per-block wall ~51k cy vs ~10k issue.
// The ea-gather path keeps paying small real wins (R15/R19/R22: -3/-6.5/-4%)
// but register residency is allocator-vetoed in all forms (plain hoist,
// bounds floor, opaque-asm pin: VGPR pinned at 80). This round: LDS-stage
// the WHOLE emb_ea table (16x128 fp32 = 8 KB). attrs are block-uniform ->
// per-msg load becomes ds_read_b64 at attr*512 + c0*4: 4-lane groups
// broadcast (free), 16 slots span 32 banks -> conflict-free. Replaces 130
// VMEM gathers/wave (~250-400cy, batched ~6 by 80-VGPR cap) with 130
// ds_reads (~120cy) and deletes the 64b addr recompute. Zero added VGPR
// (pk nibble machinery returns). LDS 34816->43008 (cap 3 blk/CU; measured
// residency ~2.1 -> not binding).
// GATE: if main dur within +-3% of 162us, ea latency is exonerated for
// good (register, pin, LDS all tried) -> plateau assessment next.
// Falsified: occupancy-floor attrs (R1/R6), LDS size/barrier scope (R7/R11),
// epilogue (R8/R9), bank conflicts (R11), B-prefetch-in-phase (R12), VALU
// width (R13), wave-parallel widening (R14/R20), ea register residency
// (R15/R19/R22), asm-confounded sync (R18). Wins: bf16-A (R16, -17%),
// bf16-B (R17, -2%), bounds floor (R19, -6.5%), 1-barrier dbuf + B-hoist
// (R21, -3%), (R22, -4%).

// Fused prep, grid 53 x 512:
//  b 0..31  : lin32 row b (4-way f-split + LDS reduce)
//  b 32..51 : w_conv -> B-fragment bf16 pre-pack with permuted N (160 frags)
//  b 52     : out[g] = b_pred[0]
__global__ __launch_bounds__(512) void prep_kernel(
    const float* __restrict__ emb_x,
    const float* __restrict__ w_ti,
    const float* __restrict__ b_ti,
    const float* __restrict__ w_conv,
    const float* __restrict__ b_pred,
    float* __restrict__ lin32,
    uint4* __restrict__ wfrag,
    float* __restrict__ out) {
  const int b = blockIdx.x, tid = threadIdx.x;
  if (b < 32) {
    __shared__ float red[4][EMB];
    const int e = tid & 127, fh = tid >> 7;      // fh in [0,4)
    const float* xr = emb_x + b * EMB;
    float s = 0.f;
    #pragma unroll 8
    for (int f = fh * 32; f < fh * 32 + 32; ++f)
      s = fmaf(xr[f], w_ti[f * EMB + e], s);
    red[fh][e] = s;
    __syncthreads();
    if (fh == 0)
      lin32[b * EMB + e] =
          b_ti[e] + ((red[0][e] + red[1][e]) + (red[2][e] + red[3][e]));
  } else if (b < 52) {
    const int id   = (b - 32) * 512 + tid;   // 160 frags * 64 lanes = 10240
    const int lane = id & 63;
    const int f    = id >> 6;         // frag index: [l][kt][u]
    const int u    = f & 7;           // N-tile (physical)
    const int t    = (f >> 3) & 3;    // K-tile
    const int l    = f >> 5;          // layer
    const int q    = lane >> 4, n = lane & 15;
    const int cN   = 2 * ((u >> 1) * 16 + n) + (u & 1);   // logical out channel
    unsigned w[4] = {0u, 0u, 0u, 0u};
    #pragma unroll
    for (int j = 0; j < 8; ++j) {
      const int kk = t * 32 + q * 8 + j;    // logical in channel (canonical)
      const float val = w_conv[l * (EMB * EMB) + kk * EMB + cN];
      const unsigned bb = bf16_rne_hi(val);
      w[j >> 1] |= (j & 1) ? bb : (bb >> 16);
    }
    wfrag[id] = make_uint4(w[0], w[1], w[2], w[3]);
  } else {
    if (tid < 64) out[tid] = b_pred[0];
  }
}

// R9 structure + packed fp32 (R13) + bf16 A/B (R16/R17) + bounds floor
// (R19) + 1-barrier dbuf/B-hoist (R21) + R23: LDS-staged emb_ea table.
__global__ __launch_bounds__(256, 2)
void i2gnn_mfma(
    const int* __restrict__ x,
    const int* __restrict__ edge_attr,
    const int* __restrict__ tuplefeat,
    const float* __restrict__ emb_x,
    const float* __restrict__ emb_tf,
    const float* __restrict__ emb_ea,
    const float* __restrict__ lin32,
    const float* __restrict__ b_conv,
    const float* __restrict__ w_pred,
    const uint4* __restrict__ wfrag,
    float* __restrict__ out)
{
  __shared__ __align__(16) unsigned fragA[2 * 64 * 68];   // 34816 B, dbuf
  __shared__ __align__(16) float eas[16 * EMB];           // 8192 B emb_ea copy

  const int tid = threadIdx.x;
  const int wv = tid >> 6, lane = tid & 63;
  const int m16 = lane & 15, q2 = lane >> 4;
  const int pc = wv * 16 + m16;        // logical pair-column this lane produces
  const int c0 = pc * 2;               // logical channels c0, c0+1

  const int i = blockIdx.x;
  const int ibase = i & ~63, io = i & 63;
  const int g = i >> 6;

  // ---- stage emb_ea table into LDS (coalesced, hidden under prologue) ----
  {
    const float4* src = (const float4*)emb_ea;
    float4* dst = (float4*)eas;
    dst[tid] = src[tid];                 // 512 float4 total
    dst[tid + 256] = src[tid + 256];
  }

  // 26 edge attrs (4 bits each) — function of i only
  unsigned pk[4] = {0u, 0u, 0u, 0u};
  #pragma unroll
  for (int m = 0; m < 26; ++m) {
    const int kg = ibase + ((io + OKv[m]) & 63);
    const unsigned a = (unsigned)edge_attr[(kg << 2) + DIv[m]];
    pk[m >> 3] |= a << ((m & 7) * 4);
  }

  // tupleinit in C-layout (packed): X2[mt][r] = v2f over channels (c0, c0+1);
  // pair ps = mt&1 (this lane: 2*q2+ps), k = (mt>>1)*4 + r.
  const int xi = x[i];
  const v2f xe = ldv2(emb_x + xi * EMB + c0);
  v2f lj[2];
  #pragma unroll
  for (int ps = 0; ps < 2; ++ps) {
    const int jn = ibase + ((io + 2 * q2 + ps) & 63);
    lj[ps] = ldv2(lin32 + x[jn] * EMB + c0);
  }
  v2f X2[4][4];   // [mt][r]
  #pragma unroll
  for (int mt = 0; mt < 4; ++mt) {
    const int ps = mt & 1, kb = (mt >> 1) * 4;
    const int t0 = (i * 8 + 2 * q2 + ps) << 3;
    const v2f xl = xe * lj[ps];
    #pragma unroll
    for (int r = 0; r < 4; ++r) {
      const int2 tf2 = *(const int2*)(tuplefeat + 2 * (t0 + kb + r));
      const int row = (c0 < 64) ? tf2.x : tf2.y;   // c0,c0+1 in same half
      const v2f tf = ldv2(emb_tf + row * 64 + (c0 & 63));
      X2[mt][r] = xl * tf;
    }
  }

  __syncthreads();   // eas staged before first msg phase reads it

  const float* eabase = eas + c0;   // per-lane channel base into the table

  for (int l = 0; l < 5; ++l) {
    unsigned* fbuf = fragA + (l & 1) * 4352;   // this layer's A-frag buffer

    // ---- message pass, packed fp32 over (c0, c0+1), ea from LDS ----
    v2f acc[2][8];   // [ps][k]
    #pragma unroll
    for (int ps = 0; ps < 2; ++ps)
      #pragma unroll
      for (int k = 0; k < 8; ++k) acc[ps][k] = (v2f){0.f, 0.f};
    #pragma unroll
    for (int m = 0; m < 26; ++m) {
      const unsigned attr = (pk[m >> 3] >> ((m & 7) * 4)) & 15u;
      const v2f e = ldv2(eabase + attr * EMB);   // ds_read_b64, broadcast groups
      const int ok = OKv[m], ol = OLv[m];
      const int mtb = 2 * (ol >> 2), rl = ol & 3;   // compile-time consts
      acc[0][ok] += X2[mtb + 0][rl] * e;            // v_pk_fma_f32
      acc[1][ok] += X2[mtb + 1][rl] * e;
    }
    // ---- pack to bf16 (RNE), straight into A-frag LDS (dbuf side l&1) ----
    #pragma unroll
    for (int ps = 0; ps < 2; ++ps)
      #pragma unroll
      for (int k = 0; k < 8; ++k) {
        const v2f a = acc[ps][k];
        const int row = (ps + 2 * (k >> 2)) * 16 + q2 * 4 + (k & 3);
        fbuf[row * 68 + pc] = cvt_pk_bf16(a.x, a.y);
      }

    // ---- B(kt=0) hoisted ABOVE the barrier: its L2 latency hides under
    //      the barrier wait; dbuf gives the compiler a barrier-free span
    //      to float it even earlier (no dependence on fragA). ----
    FragU B0, B1;
    {
      const uint4* wp0 = wfrag + (((l * 4 + 0) * 8 + 2 * wv) << 6);
      B0.q = wp0[lane];  B1.q = wp0[64 + lane];
    }

    __syncthreads();   // the ONLY barrier this layer

    // ---- MFMA: wave computes u = {2wv, 2wv+1} for all 4 M-tiles ----
    floatx4 C[2][4];
    #pragma unroll
    for (int v = 0; v < 2; ++v)
      #pragma unroll
      for (int mt = 0; mt < 4; ++mt) C[v][mt] = (floatx4){0.f, 0.f, 0.f, 0.f};

    __builtin_amdgcn_s_setprio(1);
    #pragma unroll
    for (int kt = 0; kt < 4; ++kt) {
      FragU nB0, nB1;
      if (kt < 3) {   // rotate-prefetch next kt's B under this kt's MFMAs
        const uint4* wpn = wfrag + (((l * 4 + kt + 1) * 8 + 2 * wv) << 6);
        nB0.q = wpn[lane];  nB1.q = wpn[64 + lane];
      }
      #pragma unroll
      for (int mt = 0; mt < 4; ++mt) {
        const unsigned* fa = fbuf + (mt * 16 + m16) * 68 + kt * 16 + q2 * 4;
        FragU Ah;
        Ah.q = *(const uint4*)fa;
        C[0][mt] = __builtin_amdgcn_mfma_f32_16x16x32_bf16(Ah.v, B0.v, C[0][mt], 0, 0, 0);
        C[1][mt] = __builtin_amdgcn_mfma_f32_16x16x32_bf16(Ah.v, B1.v, C[1][mt], 0, 0, 0);
      }
      if (kt < 3) { B0 = nB0; B1 = nB1; }
    }
    __builtin_amdgcn_s_setprio(0);
    // NO second barrier (dbuf): next layer packs into the other buffer;
    // WAR on this buffer is ordered via barrier(l+1) — see R21 proof.

    // ---- residual + relu, packed: combine C[0]/C[1] into v2f lanes ----
    const v2f bc = ldv2(b_conv + l * EMB + c0);
    #pragma unroll
    for (int mt = 0; mt < 4; ++mt)
      #pragma unroll
      for (int r = 0; r < 4; ++r) {
        v2f o; o.x = C[0][mt][r]; o.y = C[1][mt][r];
        o += bc;                                     // v_pk_add_f32
        o.x = fmaxf(o.x, 0.f); o.y = fmaxf(o.y, 0.f);  // v_pk_max_f32
        X2[mt][r] += o;
      }
  }

  // ---- pooling: max over k per (v, pair), dot w_pred, xor-reduce, atomic ----
  const v2f wp = ldv2(w_pred + c0);
  v2f p0 = (v2f){-3.4e38f, -3.4e38f}, p1 = p0;
  #pragma unroll
  for (int r = 0; r < 4; ++r) {
    p0.x = fmaxf(p0.x, fmaxf(X2[0][r].x, X2[2][r].x));
    p0.y = fmaxf(p0.y, fmaxf(X2[0][r].y, X2[2][r].y));
    p1.x = fmaxf(p1.x, fmaxf(X2[1][r].x, X2[3][r].x));
    p1.y = fmaxf(p1.y, fmaxf(X2[1][r].y, X2[3][r].y));
  }
  const v2f ps = (p0 + p1) * wp;
  float s = ps.x + ps.y;
  #pragma unroll
  for (int off = 32; off; off >>= 1) s += __shfl_xor(s, off, 64);
  if (lane == 0) atomicAdd(out + g, s);
}

extern "C" void kernel_launch(void* const* d_in, const int* in_sizes, int n_in,
                              void* d_out, int out_size, void* d_ws, size_t ws_size,
                              hipStream_t stream) {
  const int*   x         = (const int*)d_in[0];
  const int*   edge_attr = (const int*)d_in[1];
  const int*   tuplefeat = (const int*)d_in[2];
  const float* emb_x     = (const float*)d_in[12];
  const float* emb_ea    = (const float*)d_in[13];
  const float* emb_tf    = (const float*)d_in[14];
  const float* w_ti      = (const float*)d_in[15];
  const float* b_ti      = (const float*)d_in[16];
  const float* w_conv    = (const float*)d_in[17];
  const float* b_conv    = (const float*)d_in[18];
  const float* w_pred    = (const float*)d_in[19];
  const float* b_pred    = (const float*)d_in[20];
  float* out = (float*)d_out;
  float* lin32 = (float*)d_ws;                               // 32*128 fp32 = 16 KB
  uint4* wfrag = (uint4*)((char*)d_ws + 32 * EMB * 4);       // 160 KB B-fragments

  hipLaunchKernelGGL(prep_kernel, dim3(53), dim3(512), 0, stream,
                     emb_x, w_ti, b_ti, w_conv, b_pred, lin32, wfrag, out);
  hipLaunchKernelGGL(i2gnn_mfma, dim3(4096), dim3(256), 0, stream,
                     x, edge_attr, tuplefeat, emb_x, emb_tf, emb_ea, lin32,
                     b_conv, w_pred, wfrag, out);
}

// Round 10
// 241.464 us; speedup vs baseline: 1.1047x; 1.0706x over previous
//
#include <hip/hip_runtime.h>
#include <hip/hip_bf16.h>

#define EMB 128

typedef __attribute__((ext_vector_type(8))) short short8;   // 8 bf16 (4 VGPRs)
typedef __attribute__((ext_vector_type(4))) float floatx4;  // MFMA C/D
typedef __attribute__((ext_vector_type(2))) float v2f;      // -> v_pk_fma_f32

// 26 valid (ok, di, ol) message combos: deltas = {1,2,-1,-2}, ol = ok+delta in [0,8)
static constexpr int OKv[26] = {0,0,1,1,1,2,2,2,2,3,3,3,3,4,4,4,4,5,5,5,5,6,6,6,7,7};
static constexpr int DIv[26] = {0,1,0,1,2,0,1,2,3,0,1,2,3,0,1,2,3,0,1,2,3,0,2,3,2,3};
static constexpr int OLv[26] = {1,2,2,3,0,3,4,1,0,4,5,2,1,5,6,3,2,6,7,4,3,7,5,4,6,5};

__device__ __forceinline__ v2f ldv2(const float* p) { return *(const v2f*)p; }

// round-to-nearest-even bf16 bits of x, kept in the TOP 16 bits (low 16 zero)
__device__ __forceinline__ unsigned bf16_rne_hi(float x) {
  unsigned u = __float_as_uint(x);
  return (u + 0x7FFFu + ((u >> 16) & 1u)) & 0xFFFF0000u;
}
// HW packed cvt: a -> low 16, b -> high 16 (v_cvt_pk_bf16_f32 on gfx950)
__device__ __forceinline__ unsigned cvt_pk_bf16(float a, float b) {
  __hip_bfloat162 h = __float22bfloat162_rn(make_float2(a, b));
  unsigned r; __builtin_memcpy(&r, &h, 4); return r;
}

union FragU { unsigned u[4]; uint4 q; short8 v; };

// LOGICAL CHANNEL PERMUTATION (R9-verified): MFMA C physical position
// (u, n=lane&15) carries logical channel L(u,n) = 2*((u>>1)*16 + n) + (u&1).
// Wave wv computes u in {2wv, 2wv+1} -> lane (wv, m16) holds the ADJACENT
// logical pair c0 = 2*(wv*16+m16), c0+1. Only wfrag bakes the permutation.
//
// SESSION NOTE (R24): latency-bound; wall/block ~51k cy vs ~10k issue; all
// pipes <30%; residency pinned ~8.4 waves/CU across every resource change
// -> residency levers exhausted (R1/R6/R20). ea-load latency exonerated
// (register R15/R19/R22 refused; LDS R23 neutral-negative -> reverted).
// This round: CROSS-ROOT ILP WITHIN EACH WAVE. Two roots per 256-thread
// block, half-layer staggered: [mfmaA(l) || msgB(l)+packB] -> barrier ->
// [mfmaB(l) || msgA(l+1)+packA] -> barrier. One root's MFMA latency is
// filled by the other root's msg FMAs + ea loads (m114 overlap, in-wave,
// immune to the residency ceiling). Differs from R14's failure: base VGPR
// is 80 (was 104), acc/C time-share across roots, single buffer per root.
// setprio DROPPED (unmodeled side effects would fence the interleave).
// HAZARDS (2 barriers/layer): mfmaA(l) reads bufA written pre-barrier in
// prev region2/prologue; packB(l) overwrites bufB only after the barrier
// that followed mfmaB(l-1)'s reads; packA(l+1) (region2) overwrites bufA
// read in region1, barrier between. All WAR/RAW cross a barrier.
// GATE: VGPR 110-150 expected. dur >= 180 or VGPR > 160 -> revert R22,
// declare structural plateau (~162 us main).
// Falsified: occupancy-floor attrs (R1/R6), LDS size/barrier scope (R7/R11),
// epilogue (R8/R9), bank conflicts (R11), B-prefetch-in-phase (R12), VALU
// width (R13), wave-PARALLEL widening (R14/R20), ea residency/LDS
// (R15/R19/R22/R23), asm-confounded sync (R18). Wins: bf16-A (R16, -17%),
// bf16-B (R17, -2%), bounds floor (R19, -6.5%), 1-barrier dbuf+B-hoist
// (R21, -3%), R22 (-4%).

// Fused prep, grid 53 x 512:
//  b 0..31  : lin32 row b (4-way f-split + LDS reduce)
//  b 32..51 : w_conv -> B-fragment bf16 pre-pack with permuted N (160 frags)
//  b 52     : out[g] = b_pred[0]
__global__ __launch_bounds__(512) void prep_kernel(
    const float* __restrict__ emb_x,
    const float* __restrict__ w_ti,
    const float* __restrict__ b_ti,
    const float* __restrict__ w_conv,
    const float* __restrict__ b_pred,
    float* __restrict__ lin32,
    uint4* __restrict__ wfrag,
    float* __restrict__ out) {
  const int b = blockIdx.x, tid = threadIdx.x;
  if (b < 32) {
    __shared__ float red[4][EMB];
    const int e = tid & 127, fh = tid >> 7;      // fh in [0,4)
    const float* xr = emb_x + b * EMB;
    float s = 0.f;
    #pragma unroll 8
    for (int f = fh * 32; f < fh * 32 + 32; ++f)
      s = fmaf(xr[f], w_ti[f * EMB + e], s);
    red[fh][e] = s;
    __syncthreads();
    if (fh == 0)
      lin32[b * EMB + e] =
          b_ti[e] + ((red[0][e] + red[1][e]) + (red[2][e] + red[3][e]));
  } else if (b < 52) {
    const int id   = (b - 32) * 512 + tid;   // 160 frags * 64 lanes = 10240
    const int lane = id & 63;
    const int f    = id >> 6;         // frag index: [l][kt][u]
    const int u    = f & 7;           // N-tile (physical)
    const int t    = (f >> 3) & 3;    // K-tile
    const int l    = f >> 5;          // layer
    const int q    = lane >> 4, n = lane & 15;
    const int cN   = 2 * ((u >> 1) * 16 + n) + (u & 1);   // logical out channel
    unsigned w[4] = {0u, 0u, 0u, 0u};
    #pragma unroll
    for (int j = 0; j < 8; ++j) {
      const int kk = t * 32 + q * 8 + j;    // logical in channel (canonical)
      const float val = w_conv[l * (EMB * EMB) + kk * EMB + cN];
      const unsigned bb = bf16_rne_hi(val);
      w[j >> 1] |= (j & 1) ? bb : (bb >> 16);
    }
    wfrag[id] = make_uint4(w[0], w[1], w[2], w[3]);
  } else {
    if (tid < 64) out[tid] = b_pred[0];
  }
}

// ---- per-root phase helpers (forceinline, all indexing compile-time) ----

__device__ __forceinline__ void tuple_init(
    int i, int ibase, int io,
    const int* __restrict__ x, const int* __restrict__ edge_attr,
    const int* __restrict__ tuplefeat,
    const float* __restrict__ emb_x, const float* __restrict__ emb_tf,
    const float* __restrict__ lin32,
    int c0, int q2, v2f (&X2)[4][4], unsigned (&pk)[4])
{
  #pragma unroll
  for (int m = 0; m < 26; ++m) {
    const int kg = ibase + ((io + OKv[m]) & 63);
    const unsigned a = (unsigned)edge_attr[(kg << 2) + DIv[m]];
    pk[m >> 3] |= a << ((m & 7) * 4);
  }
  const int xi = x[i];
  const v2f xe = ldv2(emb_x + xi * EMB + c0);
  v2f lj[2];
  #pragma unroll
  for (int ps = 0; ps < 2; ++ps) {
    const int jn = ibase + ((io + 2 * q2 + ps) & 63);
    lj[ps] = ldv2(lin32 + x[jn] * EMB + c0);
  }
  #pragma unroll
  for (int mt = 0; mt < 4; ++mt) {
    const int ps = mt & 1, kb = (mt >> 1) * 4;
    const int t0 = (i * 8 + 2 * q2 + ps) << 3;
    const v2f xl = xe * lj[ps];
    #pragma unroll
    for (int r = 0; r < 4; ++r) {
      const int2 tf2 = *(const int2*)(tuplefeat + 2 * (t0 + kb + r));
      const int row = (c0 < 64) ? tf2.x : tf2.y;   // c0,c0+1 in same half
      const v2f tf = ldv2(emb_tf + row * 64 + (c0 & 63));
      X2[mt][r] = xl * tf;
    }
  }
}

__device__ __forceinline__ void msg_pack(
    const v2f (&X2)[4][4], const unsigned (&pk)[4],
    const float* __restrict__ emb_ea,
    int c0, int q2, int pc, unsigned* fbuf)
{
  v2f acc[2][8];   // [ps][k]
  #pragma unroll
  for (int ps = 0; ps < 2; ++ps)
    #pragma unroll
    for (int k = 0; k < 8; ++k) acc[ps][k] = (v2f){0.f, 0.f};
  #pragma unroll
  for (int m = 0; m < 26; ++m) {
    const unsigned attr = (pk[m >> 3] >> ((m & 7) * 4)) & 15u;
    const v2f e = ldv2(emb_ea + attr * EMB + c0);
    const int ok = OKv[m], ol = OLv[m];
    const int mtb = 2 * (ol >> 2), rl = ol & 3;   // compile-time consts
    acc[0][ok] += X2[mtb + 0][rl] * e;            // v_pk_fma_f32
    acc[1][ok] += X2[mtb + 1][rl] * e;
  }
  #pragma unroll
  for (int ps = 0; ps < 2; ++ps)
    #pragma unroll
    for (int k = 0; k < 8; ++k) {
      const v2f a = acc[ps][k];
      const int row = (ps + 2 * (k >> 2)) * 16 + q2 * 4 + (k & 3);
      fbuf[row * 68 + pc] = cvt_pk_bf16(a.x, a.y);
    }
}

__device__ __forceinline__ void mfma_resid(
    const unsigned* fbuf, const uint4* __restrict__ wfrag, int l,
    int wv, int lane, int m16, int q2, v2f bc, v2f (&X2)[4][4])
{
  floatx4 C[2][4];
  #pragma unroll
  for (int v = 0; v < 2; ++v)
    #pragma unroll
    for (int mt = 0; mt < 4; ++mt) C[v][mt] = (floatx4){0.f, 0.f, 0.f, 0.f};
  FragU B0, B1;
  {
    const uint4* wp0 = wfrag + (((l * 4 + 0) * 8 + 2 * wv) << 6);
    B0.q = wp0[lane];  B1.q = wp0[64 + lane];
  }
  #pragma unroll
  for (int kt = 0; kt < 4; ++kt) {
    FragU nB0, nB1;
    if (kt < 3) {   // rotate-prefetch next kt's B under this kt's MFMAs
      const uint4* wpn = wfrag + (((l * 4 + kt + 1) * 8 + 2 * wv) << 6);
      nB0.q = wpn[lane];  nB1.q = wpn[64 + lane];
    }
    #pragma unroll
    for (int mt = 0; mt < 4; ++mt) {
      const unsigned* fa = fbuf + (mt * 16 + m16) * 68 + kt * 16 + q2 * 4;
      FragU Ah;
      Ah.q = *(const uint4*)fa;
      C[0][mt] = __builtin_amdgcn_mfma_f32_16x16x32_bf16(Ah.v, B0.v, C[0][mt], 0, 0, 0);
      C[1][mt] = __builtin_amdgcn_mfma_f32_16x16x32_bf16(Ah.v, B1.v, C[1][mt], 0, 0, 0);
    }
    if (kt < 3) { B0 = nB0; B1 = nB1; }
  }
  #pragma unroll
  for (int mt = 0; mt < 4; ++mt)
    #pragma unroll
    for (int r = 0; r < 4; ++r) {
      v2f o; o.x = C[0][mt][r]; o.y = C[1][mt][r];
      o += bc;                                     // v_pk_add_f32
      o.x = fmaxf(o.x, 0.f); o.y = fmaxf(o.y, 0.f);  // v_pk_max_f32
      X2[mt][r] += o;
    }
}

__device__ __forceinline__ float pool_dot(const v2f (&X2)[4][4], v2f wp)
{
  v2f p0 = (v2f){-3.4e38f, -3.4e38f}, p1 = p0;
  #pragma unroll
  for (int r = 0; r < 4; ++r) {
    p0.x = fmaxf(p0.x, fmaxf(X2[0][r].x, X2[2][r].x));
    p0.y = fmaxf(p0.y, fmaxf(X2[0][r].y, X2[2][r].y));
    p1.x = fmaxf(p1.x, fmaxf(X2[1][r].x, X2[3][r].x));
    p1.y = fmaxf(p1.y, fmaxf(X2[1][r].y, X2[3][r].y));
  }
  const v2f ps = (p0 + p1) * wp;
  return ps.x + ps.y;
}

// R9 structure + packed fp32 (R13) + bf16 A/B (R16/R17) + bounds floor
// (R19) + R24: two roots per block, half-layer staggered in-wave pipeline.
__global__ __launch_bounds__(256, 2)
void i2gnn_mfma(
    const int* __restrict__ x,
    const int* __restrict__ edge_attr,
    const int* __restrict__ tuplefeat,
    const float* __restrict__ emb_x,
    const float* __restrict__ emb_tf,
    const float* __restrict__ emb_ea,
    const float* __restrict__ lin32,
    const float* __restrict__ b_conv,
    const float* __restrict__ w_pred,
    const uint4* __restrict__ wfrag,
    float* __restrict__ out)
{
  __shared__ __align__(16) unsigned frag[2 * 64 * 68];   // 34816 B: bufA | bufB
  unsigned* bufA = frag;
  unsigned* bufB = frag + 4352;

  const int tid = threadIdx.x;
  const int wv = tid >> 6, lane = tid & 63;
  const int m16 = lane & 15, q2 = lane >> 4;
  const int pc = wv * 16 + m16;        // logical pair-column this lane produces
  const int c0 = pc * 2;               // logical channels c0, c0+1

  const int iA = blockIdx.x * 2;       // two roots, same graph & 64-group
  const int iB = iA + 1;
  const int ibase = iA & ~63;
  const int ioA = iA & 63, ioB = iB & 63;
  const int g = iA >> 6;               // iB >> 6 identical (bit0 irrelevant)

  v2f X2A[4][4], X2B[4][4];
  unsigned pkA[4] = {0u,0u,0u,0u}, pkB[4] = {0u,0u,0u,0u};
  tuple_init(iA, ibase, ioA, x, edge_attr, tuplefeat, emb_x, emb_tf, lin32,
             c0, q2, X2A, pkA);
  tuple_init(iB, ibase, ioB, x, edge_attr, tuplefeat, emb_x, emb_tf, lin32,
             c0, q2, X2B, pkB);

  // prologue: fill bufA for layer 0
  msg_pack(X2A, pkA, emb_ea, c0, q2, pc, bufA);
  __syncthreads();

  for (int l = 0; l < 5; ++l) {
    const v2f bc = ldv2(b_conv + l * EMB + c0);   // shared: same c0 both roots

    // ---- REGION 1: mfmaA(l) || msgB(l)+packB — independent chains; the
    //      scheduler fills mfmaA's LDS/MFMA latency with msgB VALU+loads ----
    mfma_resid(bufA, wfrag, l, wv, lane, m16, q2, bc, X2A);
    msg_pack(X2B, pkB, emb_ea, c0, q2, pc, bufB);
    __syncthreads();

    // ---- REGION 2: mfmaB(l) || msgA(l+1)+packA ----
    mfma_resid(bufB, wfrag, l, wv, lane, m16, q2, bc, X2B);
    if (l < 4) {
      msg_pack(X2A, pkA, emb_ea, c0, q2, pc, bufA);
      __syncthreads();
    }
  }

  // ---- pooling both roots, shared shuffle-reduce, single atomic ----
  const v2f wp = ldv2(w_pred + c0);
  float s = pool_dot(X2A, wp) + pool_dot(X2B, wp);
  #pragma unroll
  for (int off = 32; off; off >>= 1) s += __shfl_xor(s, off, 64);
  if (lane == 0) atomicAdd(out + g, s);
}

extern "C" void kernel_launch(void* const* d_in, const int* in_sizes, int n_in,
                              void* d_out, int out_size, void* d_ws, size_t ws_size,
                              hipStream_t stream) {
  const int*   x         = (const int*)d_in[0];
  const int*   edge_attr = (const int*)d_in[1];
  const int*   tuplefeat = (const int*)d_in[2];
  const float* emb_x     = (const float*)d_in[12];
  const float* emb_ea    = (const float*)d_in[13];
  const float* emb_tf    = (const float*)d_in[14];
  const float* w_ti      = (const float*)d_in[15];
  const float* b_ti      = (const float*)d_in[16];
  const float* w_conv    = (const float*)d_in[17];
  const float* b_conv    = (const float*)d_in[18];
  const float* w_pred    = (const float*)d_in[19];
  const float* b_pred    = (const float*)d_in[20];
  float* out = (float*)d_out;
  float* lin32 = (float*)d_ws;                               // 32*128 fp32 = 16 KB
  uint4* wfrag = (uint4*)((char*)d_ws + 32 * EMB * 4);       // 160 KB B-fragments

  hipLaunchKernelGGL(prep_kernel, dim3(53), dim3(512), 0, stream,
                     emb_x, w_ti, b_ti, w_conv, b_pred, lin32, wfrag, out);
  hipLaunchKernelGGL(i2gnn_mfma, dim3(2048), dim3(256), 0, stream,
                     x, edge_attr, tuplefeat, emb_x, emb_tf, emb_ea, lin32,
                     b_conv, w_pred, wfrag, out);
}